// Round 1
// baseline (122.445 us; speedup 1.0000x reference)
//
#include <hip/hip_runtime.h>
#include <math.h>

#define TEMP_INV 10.0f     // 1 / TEMPERATURE
#define EPSN 1e-8f

// Butterfly sum across the full 64-lane wave; every lane ends with the total.
__device__ __forceinline__ float wave_sum(float v) {
    #pragma unroll
    for (int off = 32; off > 0; off >>= 1)
        v += __shfl_xor(v, off, 64);
    return v;
}

// K1: S-partials over the memory bank. Wave-per-row, float2 per lane (D=128).
// grid 256 x 1024 threads = 4096 waves, 16 rows/wave. Writes P[block][128].
__global__ __launch_bounds__(1024) void k_memsum(const float2* __restrict__ mem,
                                                 float* __restrict__ P, int M) {
    const int tid  = threadIdx.x;
    const int lane = tid & 63;
    const int w    = tid >> 6;                 // 0..15
    const int gw   = blockIdx.x * 16 + w;
    const int GW   = gridDim.x * 16;

    float a0 = 0.f, a1 = 0.f;
    for (int m = gw; m < M; m += GW) {
        float2 v = mem[m * 64 + lane];         // coalesced 512B/wave
        float ss = wave_sum(v.x * v.x + v.y * v.y);
        float inv = 1.0f / fmaxf(sqrtf(ss), EPSN);
        a0 += v.x * inv;
        a1 += v.y * inv;
    }

    __shared__ float sacc[16][128];
    sacc[w][2 * lane]     = a0;                // 2-way LDS aliasing: free
    sacc[w][2 * lane + 1] = a1;
    __syncthreads();
    if (tid < 128) {
        float s = 0.f;
        #pragma unroll
        for (int i = 0; i < 16; ++i) s += sacc[i][tid];
        P[blockIdx.x * 128 + tid] = s;
    }
}

// K2: each block reduces P -> S in LDS (L2-resident, redundant across blocks),
// then wave-per-row loss over N samples. grid 32 x 256 threads.
__global__ __launch_bounds__(256) void k_loss(const float2* __restrict__ real,
                                              const float2* __restrict__ pert,
                                              const float* __restrict__ P,
                                              float* __restrict__ L,
                                              int N, int NPART) {
    __shared__ float s[128];
    __shared__ float s2[128];
    const int t = threadIdx.x;
    {
        const int d    = t & 127;
        const int half = NPART >> 1;
        const int j0   = (t >> 7) * half;
        float acc = 0.f;
        for (int j = j0; j < j0 + half; ++j) acc += P[j * 128 + d];  // coalesced per j
        if (t < 128) s[d] = acc; else s2[d] = acc;
    }
    __syncthreads();
    if (t < 128) s[t] += s2[t];
    __syncthreads();

    const int lane = t & 63;
    const int w    = t >> 6;                    // 0..3
    const int gw   = blockIdx.x * 4 + w;
    const int GW   = gridDim.x * 4;
    const float2 sv = make_float2(s[2 * lane], s[2 * lane + 1]);

    float lsum = 0.f;
    for (int n = gw; n < N; n += GW) {
        float2 r = real[n * 64 + lane];
        float2 p = pert[n * 64 + lane];
        float ssr = wave_sum(r.x * r.x + r.y * r.y);
        float ssp = wave_sum(p.x * p.x + p.y * p.y);
        float drp = wave_sum(r.x * p.x + r.y * p.y);
        float drs = wave_sum(r.x * sv.x + r.y * sv.y);
        float nr  = fmaxf(sqrtf(ssr), EPSN);
        float npf = fmaxf(sqrtf(ssp), EPSN);
        float pos = drp / (nr * npf) * TEMP_INV;
        float neg = drs / nr * TEMP_INV;
        float mx  = fmaxf(pos, neg);
        float lse = mx + logf(expf(pos - mx) + expf(neg - mx));
        lsum += lse - pos;                      // identical on all lanes
    }

    __shared__ float wl[4];
    if (lane == 0) wl[w] = lsum;
    __syncthreads();
    if (t == 0) L[blockIdx.x] = wl[0] + wl[1] + wl[2] + wl[3];
}

// K3: reduce the 32 block partials and write the mean.
__global__ void k_final(const float* __restrict__ L, float* __restrict__ out,
                        int nL, float invN) {
    float v = (threadIdx.x < nL) ? L[threadIdx.x] : 0.f;
    v = wave_sum(v);
    if (threadIdx.x == 0) out[0] = v * invN;
}

extern "C" void kernel_launch(void* const* d_in, const int* in_sizes, int n_in,
                              void* d_out, int out_size, void* d_ws, size_t ws_size,
                              hipStream_t stream) {
    const float* real = (const float*)d_in[0];   // [N,128]
    const float* pert = (const float*)d_in[1];   // [N,128]
    const float* memb = (const float*)d_in[2];   // [M,128]
    float* out = (float*)d_out;

    const int D = 128;
    const int N = in_sizes[0] / D;               // 1024
    const int M = in_sizes[2] / D;               // 65536

    const int NPART = 256;                       // K1 grid = #partials
    float* P = (float*)d_ws;                     // [NPART][128]
    float* L = P + NPART * 128;                  // [32]

    k_memsum<<<NPART, 1024, 0, stream>>>((const float2*)memb, P, M);
    k_loss<<<32, 256, 0, stream>>>((const float2*)real, (const float2*)pert,
                                   P, L, N, NPART);
    k_final<<<1, 64, 0, stream>>>(L, out, 32, 1.0f / (float)N);
}

// Round 2
// 86.110 us; speedup vs baseline: 1.4220x; 1.4220x over previous
//
#include <hip/hip_runtime.h>
#include <math.h>

#define TEMP_INV 10.0f     // 1 / TEMPERATURE
#define EPSN 1e-8f

// Butterfly sum across the full 64-lane wave; every lane ends with the total.
__device__ __forceinline__ float wave_sum(float v) {
    #pragma unroll
    for (int off = 32; off > 0; off >>= 1)
        v += __shfl_xor(v, off, 64);
    return v;
}

// Four independent butterflies interleaved so the ~35-cyc swizzle latencies
// overlap instead of forming one serial chain.
__device__ __forceinline__ void wave_sum4(float& v0, float& v1, float& v2, float& v3) {
    #pragma unroll
    for (int off = 32; off > 0; off >>= 1) {
        v0 += __shfl_xor(v0, off, 64);
        v1 += __shfl_xor(v1, off, 64);
        v2 += __shfl_xor(v2, off, 64);
        v3 += __shfl_xor(v3, off, 64);
    }
}

// K1: partial sums of row-normalized memory bank. Wave-per-row, float2/lane
// (D=128 -> 512B coalesced per wave-load). 4-way row interleave for ILP.
// grid 256 x 1024 threads = 4096 waves. Writes P[block][128].
__global__ __launch_bounds__(1024) void k_memsum(const float2* __restrict__ mem,
                                                 float* __restrict__ P, int M) {
    const int tid  = threadIdx.x;
    const int lane = tid & 63;
    const int w    = tid >> 6;                 // 0..15
    const int gw   = blockIdx.x * 16 + w;
    const int GW   = gridDim.x * 16;           // 4096

    float a0 = 0.f, a1 = 0.f;

    int m = gw;
    // fast path: 4 rows in flight (M=65536, GW=4096 -> exactly 4 iterations)
    for (; m + 3 * GW < M; m += 4 * GW) {
        float2 v0 = mem[(m + 0 * GW) * 64 + lane];
        float2 v1 = mem[(m + 1 * GW) * 64 + lane];
        float2 v2 = mem[(m + 2 * GW) * 64 + lane];
        float2 v3 = mem[(m + 3 * GW) * 64 + lane];
        float s0 = v0.x * v0.x + v0.y * v0.y;
        float s1 = v1.x * v1.x + v1.y * v1.y;
        float s2 = v2.x * v2.x + v2.y * v2.y;
        float s3 = v3.x * v3.x + v3.y * v3.y;
        wave_sum4(s0, s1, s2, s3);
        float i0 = 1.0f / fmaxf(sqrtf(s0), EPSN);
        float i1 = 1.0f / fmaxf(sqrtf(s1), EPSN);
        float i2 = 1.0f / fmaxf(sqrtf(s2), EPSN);
        float i3 = 1.0f / fmaxf(sqrtf(s3), EPSN);
        a0 += v0.x * i0 + v1.x * i1 + v2.x * i2 + v3.x * i3;
        a1 += v0.y * i0 + v1.y * i1 + v2.y * i2 + v3.y * i3;
    }
    for (; m < M; m += GW) {                   // remainder (not taken at M=65536)
        float2 v = mem[m * 64 + lane];
        float ss = wave_sum(v.x * v.x + v.y * v.y);
        float inv = 1.0f / fmaxf(sqrtf(ss), EPSN);
        a0 += v.x * inv;
        a1 += v.y * inv;
    }

    __shared__ float sacc[16][128];
    sacc[w][2 * lane]     = a0;                // 2-way LDS aliasing: free
    sacc[w][2 * lane + 1] = a1;
    __syncthreads();
    if (tid < 128) {
        float s = 0.f;
        #pragma unroll
        for (int i = 0; i < 16; ++i) s += sacc[i][tid];
        P[blockIdx.x * 128 + tid] = s;
    }
}

// K2: each block redundantly reduces P[256][128] -> S in LDS with a fully
// unrolled 8-group split (32 outstanding loads/thread, one latency window),
// then 16 waves/block do the per-sample loss. grid 32 x 1024 threads.
__global__ __launch_bounds__(1024) void k_loss(const float2* __restrict__ real,
                                               const float2* __restrict__ pert,
                                               const float* __restrict__ P,
                                               float* __restrict__ L,
                                               int N) {
    __shared__ float red[8][128];
    __shared__ float s[128];
    const int t = threadIdx.x;
    {
        const int d = t & 127;
        const int g = t >> 7;                  // 0..7, 32 rows each
        float acc = 0.f;
        #pragma unroll
        for (int j = 0; j < 32; ++j)
            acc += P[(g * 32 + j) * 128 + d];  // coalesced per j, 32 in flight
        red[g][d] = acc;
    }
    __syncthreads();
    if (t < 128) {
        float v = 0.f;
        #pragma unroll
        for (int i = 0; i < 8; ++i) v += red[i][t];
        s[t] = v;
    }
    __syncthreads();

    const int lane = t & 63;
    const int w    = t >> 6;                   // 0..15
    const int gw   = blockIdx.x * 16 + w;      // 0..511
    const int GW   = gridDim.x * 16;           // 512
    const float2 sv = make_float2(s[2 * lane], s[2 * lane + 1]);

    float lsum = 0.f;
    for (int n = gw; n < N; n += GW) {         // 2 iterations at N=1024
        float2 r = real[n * 64 + lane];
        float2 p = pert[n * 64 + lane];
        float ssr = r.x * r.x + r.y * r.y;
        float ssp = p.x * p.x + p.y * p.y;
        float drp = r.x * p.x + r.y * p.y;
        float drs = r.x * sv.x + r.y * sv.y;
        wave_sum4(ssr, ssp, drp, drs);         // 4 chains overlap
        float nr  = fmaxf(sqrtf(ssr), EPSN);
        float npf = fmaxf(sqrtf(ssp), EPSN);
        float pos = drp / (nr * npf) * TEMP_INV;
        float neg = drs / nr * TEMP_INV;
        float mx  = fmaxf(pos, neg);
        float lse = mx + __logf(__expf(pos - mx) + __expf(neg - mx));
        lsum += lse - pos;                     // identical on all lanes
    }

    __shared__ float wl[16];
    if (lane == 0) wl[w] = lsum;
    __syncthreads();
    if (t == 0) {
        float v = 0.f;
        #pragma unroll
        for (int i = 0; i < 16; ++i) v += wl[i];
        L[blockIdx.x] = v;
    }
}

// K3: reduce the 32 block partials and write the mean.
__global__ void k_final(const float* __restrict__ L, float* __restrict__ out,
                        int nL, float invN) {
    float v = (threadIdx.x < nL) ? L[threadIdx.x] : 0.f;
    v = wave_sum(v);
    if (threadIdx.x == 0) out[0] = v * invN;
}

extern "C" void kernel_launch(void* const* d_in, const int* in_sizes, int n_in,
                              void* d_out, int out_size, void* d_ws, size_t ws_size,
                              hipStream_t stream) {
    const float* real = (const float*)d_in[0];   // [N,128]
    const float* pert = (const float*)d_in[1];   // [N,128]
    const float* memb = (const float*)d_in[2];   // [M,128]
    float* out = (float*)d_out;

    const int D = 128;
    const int N = in_sizes[0] / D;               // 1024
    const int M = in_sizes[2] / D;               // 65536

    const int NPART = 256;                       // K1 grid = #partials
    float* P = (float*)d_ws;                     // [NPART][128]
    float* L = P + NPART * 128;                  // [32]

    k_memsum<<<NPART, 1024, 0, stream>>>((const float2*)memb, P, M);
    k_loss<<<32, 1024, 0, stream>>>((const float2*)real, (const float2*)pert,
                                    P, L, N);
    k_final<<<1, 64, 0, stream>>>(L, out, 32, 1.0f / (float)N);
}